// Round 23
// baseline (628.050 us; speedup 1.0000x reference)
//
#include <hip/hip_runtime.h>
#include <math.h>

#define HID 64
#define NCLS 20
#define EPS_CLS 1e-5f
#define EPS_AL 1e-6f
#define NCMAX 10240
#define NWORDS ((NCMAX + 31) / 32 + 1)
#define MAXMARK 192
#define NSEG 8
#define STILE 512

__device__ __forceinline__ float relu_(float x){ return x > 0.f ? x : 0.f; }

__device__ __forceinline__ float pin(float v){
  asm volatile("" : "+v"(v));
  return v;
}
__device__ __forceinline__ float mulrn_b(float a, float b){ return pin(__fmul_rn(a,b)); }
__device__ __forceinline__ float addrn_b(float a, float b){ return pin(__fadd_rn(a,b)); }
__device__ __forceinline__ float subrn_b(float a, float b){ return pin(__fsub_rn(a,b)); }

__device__ __forceinline__ float np_norm2(float x, float y, float z){
  return addrn_b(addrn_b(mulrn_b(x,x), mulrn_b(y,y)), mulrn_b(z,z));
}

// exact numpy-twin lattice d2 (verified R18-R22)
__device__ __forceinline__ float lattice_d2(float qx, float qy, float qz, float n2,
                                            float cx, float cy, float cz, float m2){
  float p0  = mulrn_b(qx, cx);
  float dot = pin(fmaf(qz, cz, fmaf(qy, cy, p0)));
  float nm  = addrn_b(n2, m2);
  float t2d = mulrn_b(2.0f, dot);
  return subrn_b(nm, t2d);
}

// ---------------- Kernel A: conv_cls head (unchanged, passes) ----------------
__global__ void __launch_bounds__(64) cls_head_kernel(
    const float* __restrict__ feats, const float* __restrict__ w1,
    const float* __restrict__ bn_g, const float* __restrict__ bn_b,
    const float* __restrict__ bn_m, const float* __restrict__ bn_v,
    const float* __restrict__ w2, const float* __restrict__ b2,
    float* __restrict__ out, int R)
{
  __shared__ float s1[HID], t1[HID];
  int tx = threadIdx.x;
  if (tx < HID) {
    float s = bn_g[tx] / sqrtf(bn_v[tx] + EPS_CLS);
    s1[tx] = s;
    t1[tx] = bn_b[tx] - bn_m[tx] * s;
  }
  __syncthreads();
  int r = blockIdx.x * 64 + tx;
  if (r >= R) return;
  float x[HID];
  const float4* xr = (const float4*)(feats + (size_t)r * HID);
  #pragma unroll
  for (int i = 0; i < 16; i++) {
    float4 t = xr[i];
    x[4*i+0]=t.x; x[4*i+1]=t.y; x[4*i+2]=t.z; x[4*i+3]=t.w;
  }
  float o[NCLS];
  #pragma unroll
  for (int c = 0; c < NCLS; c++) o[c] = b2[c];
  #pragma unroll
  for (int j = 0; j < HID; j++) {
    float acc = 0.f;
    #pragma unroll
    for (int k = 0; k < HID; k++) acc = fmaf(x[k], w1[k*HID + j], acc);
    float h = relu_(acc * s1[j] + t1[j]);
    #pragma unroll
    for (int c = 0; c < NCLS; c++) o[c] = fmaf(h, w2[j*NCLS + c], o[c]);
  }
  float4* op = (float4*)(out + (size_t)r * NCLS);
  #pragma unroll
  for (int i = 0; i < 5; i++) op[i] = make_float4(o[4*i], o[4*i+1], o[4*i+2], o[4*i+3]);
}

// ---------------- Kernel B1a: pass 1 — branchless per-segment screen minima ----------------
// s = (half_n2 + half_m2) - dot  (cheap deterministic approx of d2/2, +-2e-3)
// half_m2 = 0.5f * exact m2 (lossless), staged in LDS tile.w.
__global__ void __launch_bounds__(256) knn_min_kernel(
    const float4* __restrict__ coords, const float4* __restrict__ pts,
    float* __restrict__ pmin, int NC, int NP, int nseg)
{
  __shared__ float4 tile[STILE];
  int frame = blockIdx.z;
  int seg   = blockIdx.y;
  int tid   = threadIdx.x;
  int q = blockIdx.x * 256 + tid;
  bool valid = (q < NP);

  float qx=0.f, qy=0.f, qz=0.f, hn2=0.f;
  if (valid) {
    float4 p = pts[(size_t)frame * NP + q];
    qx=p.y; qy=p.z; qz=p.w;
    hn2 = 0.5f * np_norm2(qx,qy,qz);
  }
  int SL = (NC + nseg - 1) / nseg;
  int c0 = seg * SL, c1 = min(NC, c0 + SL);
  float smin = 1e30f;
  const float4* C = coords + (size_t)frame * NC;

  for (int t = c0; t < c1; t += STILE) {
    int n = min(STILE, c1 - t);
    __syncthreads();
    for (int k = tid; k < n; k += 256) {
      float4 cr = C[t + k];
      tile[k] = make_float4(cr.y, cr.z, cr.w, 0.5f * np_norm2(cr.y, cr.z, cr.w));
    }
    __syncthreads();
    for (int j = 0; j < n; j++) {
      float4 c = tile[j];
      float dot = fmaf(qz, c.z, fmaf(qy, c.y, qx * c.x));
      float s = (hn2 + c.w) - dot;
      smin = fminf(smin, s);
    }
  }
  if (valid) pmin[(size_t)(frame * NP + q) * nseg + seg] = smin;
}

// ---------------- Kernel B1b: pass 2 — screened exact top-4 partials ----------------
// tau = 4th smallest of segment minima => >=4 candidates have s <= tau, so the
// global 4th lattice d2 <= 2*tau + 4e-3. Screen keeps s <= tau + 0.05 (margin
// covers screen-vs-lattice rounding both ways) -> every true top-4 member,
// including exact boundary ties, survives. m2 = 2*half_m2 is bit-exact.
__global__ void __launch_bounds__(256) knn_scan_kernel(
    const float4* __restrict__ coords, const float4* __restrict__ pts,
    const float* __restrict__ pmin,
    float4* __restrict__ pd, int4* __restrict__ pi,
    int NC, int NP, int nseg)
{
  __shared__ float4 tile[STILE];
  int frame = blockIdx.z;
  int seg   = blockIdx.y;
  int tid   = threadIdx.x;
  int q = blockIdx.x * 256 + tid;
  bool valid = (q < NP);

  float qx=0.f, qy=0.f, qz=0.f, n2=0.f, hn2=0.f, scr=1e30f;
  if (valid) {
    float4 p = pts[(size_t)frame * NP + q];
    qx=p.y; qy=p.z; qz=p.w;
    n2  = np_norm2(qx,qy,qz);
    hn2 = 0.5f * n2;
    // tau = 4th smallest of nseg minima (branchless 4-min network)
    float m0=1e30f, m1=1e30f, m2n=1e30f, m3n=1e30f;
    const float* pm = pmin + (size_t)(frame * NP + q) * nseg;
    for (int s = 0; s < nseg; s++) {
      float v = pm[s];
      float t0 = fmaxf(m0, v);  m0 = fminf(m0, v);
      float t1 = fmaxf(m1, t0); m1 = fminf(m1, t0);
      float t2 = fmaxf(m2n, t1); m2n = fminf(m2n, t1);
      m3n = fminf(m3n, t2);
    }
    scr = m3n + 0.05f;           // nseg<4 -> m3n=1e30 -> keep all (safe)
  }
  int SL = (NC + nseg - 1) / nseg;
  int c0 = seg * SL, c1 = min(NC, c0 + SL);
  float d0=1e30f, d1=1e30f, d2v=1e30f, d3=1e30f;
  int   i0=-1, i1=-1, i2=-1;
  const float4* C = coords + (size_t)frame * NC;

  for (int t = c0; t < c1; t += STILE) {
    int n = min(STILE, c1 - t);
    __syncthreads();
    for (int k = tid; k < n; k += 256) {
      float4 cr = C[t + k];
      tile[k] = make_float4(cr.y, cr.z, cr.w, 0.5f * np_norm2(cr.y, cr.z, cr.w));
    }
    __syncthreads();
    for (int j = 0; j < n; j++) {
      float4 c = tile[j];
      float dotf = fmaf(qz, c.z, fmaf(qy, c.y, qx * c.x));
      float s = (hn2 + c.w) - dotf;
      if (s <= scr) {                       // rare (~5% any-lane)
        float m2 = 2.0f * c.w;              // exact recovery of staged m2
        float dd = lattice_d2(qx,qy,qz,n2, c.x,c.y,c.z,m2);
        if (dd < d3) {
          int ci = t + j;
          if (dd < d1) {
            if (dd < d0) { d3=d2v; d2v=d1;i2=i1; d1=d0;i1=i0; d0=dd;i0=ci; }
            else         { d3=d2v; d2v=d1;i2=i1; d1=dd;i1=ci; }
          } else {
            if (dd < d2v){ d3=d2v; d2v=dd;i2=ci; }
            else         { d3=dd; }
          }
        }
      }
    }
  }
  if (valid) {
    size_t base = (size_t)(frame * NP + q) * nseg + seg;
    pd[base] = make_float4(d0, d1, d2v, d3);
    pi[base] = make_int4(i0, i1, i2, -1);
  }
}

// ---------------- Kernel B1c: merge partials -> top-3 + boundary-tie mark (R22, passes) ----------------
__global__ void __launch_bounds__(256) knn_merge_kernel(
    const float4* __restrict__ pd, const int4* __restrict__ pi,
    float* __restrict__ wd, int* __restrict__ wi,
    int* __restrict__ mark_cnt, int* __restrict__ mark_rows,
    int RP, int nseg)
{
  int row = blockIdx.x * 256 + threadIdx.x;
  if (row >= RP) return;
  float m0=1e30f, m1=1e30f, m2v=1e30f, m3=1e30f;
  int   j0=0, j1=0, j2=0;
  for (int s = 0; s < nseg; s++) {
    float4 d = pd[(size_t)row * nseg + s];
    int4  ii = pi[(size_t)row * nseg + s];
    float dv[4] = { d.x, d.y, d.z, d.w };
    int   iv[4] = { ii.x, ii.y, ii.z, -1 };
    #pragma unroll
    for (int r = 0; r < 4; r++) {
      float dd = dv[r]; int jj = iv[r];
      if (dd < m3) {
        if (dd < m1) {
          if (dd < m0) { m3=m2v; m2v=m1;j2=j1; m1=m0;j1=j0; m0=dd;j0=jj; }
          else         { m3=m2v; m2v=m1;j2=j1; m1=dd;j1=jj; }
        } else {
          if (dd < m2v){ m3=m2v; m2v=dd;j2=jj; }
          else         { m3=dd; }
        }
      }
    }
  }
  size_t base = (size_t)row * 3;
  wd[base+0]=m0; wd[base+1]=m1; wd[base+2]=m2v;
  wi[base+0]=j0; wi[base+1]=j1; wi[base+2]=j2;
  if (m2v == m3) {
    int slot = atomicAdd(mark_cnt, 1);
    if (slot < MAXMARK) mark_rows[slot] = row;
  }
}

// ---------------- Kernel B1.5: block-PARALLEL exact numpy argsort head (R21/22, passes) ----------------
__global__ void __launch_bounds__(256) tie_resort_kernel(
    const float4* __restrict__ coords, const float4* __restrict__ pts,
    const int* __restrict__ mark_cnt, const int* __restrict__ mark_rows,
    float* __restrict__ wd, int* __restrict__ wi, int NC, int NP)
{
  __shared__ unsigned short t[NCMAX];
  __shared__ unsigned short Rpos[NCMAX];
  __shared__ unsigned int abit[NWORDS], bbit[NWORDS];
  __shared__ int scanA[256], scanB[256];
  __shared__ int s_pl, s_pr, s_sp, s_state, s_K, s_LK;
  __shared__ float s_vp, s_q[4], vloc[16];
  __shared__ int s_slo[64], s_shi[64];

  int cnt = *mark_cnt; if (cnt > MAXMARK) cnt = MAXMARK;
  int b = blockIdx.x;
  if (b >= cnt) return;
  int row = mark_rows[b];
  int frame = row / NP;
  int q = row - frame * NP;
  int tid = threadIdx.x;

  if (tid == 0) {
    float4 p = pts[(size_t)frame * NP + q];
    s_q[0]=p.y; s_q[1]=p.z; s_q[2]=p.w;
    s_q[3]=np_norm2(p.y,p.z,p.w);
    s_pl = 0; s_pr = NC - 1; s_sp = 0; s_state = 0;
  }
  for (int i = tid; i < NC; i += 256) t[i] = (unsigned short)i;
  __syncthreads();
  float qx=s_q[0], qy=s_q[1], qz=s_q[2], n2=s_q[3];
  const float4* C = coords + (size_t)frame * NC;

  auto V = [&](int p)->float {
    float4 c = C[t[p]];
    float m2 = np_norm2(c.y, c.z, c.w);
    return lattice_d2(qx,qy,qz,n2, c.y,c.z,c.w,m2);
  };

  for (;;) {
    __syncthreads();
    if (s_state) break;
    int pl = s_pl, pr = s_pr;

    if (pr - pl > 15) {
      if (tid == 0) {
        int pm = pl + ((pr - pl) >> 1);
        unsigned short tmp;
        if (V(pm) < V(pl)) { tmp=t[pm]; t[pm]=t[pl]; t[pl]=tmp; }
        if (V(pr) < V(pm)) { tmp=t[pr]; t[pr]=t[pm]; t[pm]=tmp; }
        if (V(pm) < V(pl)) { tmp=t[pm]; t[pm]=t[pl]; t[pl]=tmp; }
        s_vp = V(pm);
        tmp=t[pm]; t[pm]=t[pr-1]; t[pr-1]=tmp;
        s_K = 0;
      }
      __syncthreads();
      float vp = s_vp;
      int M = pr - pl + 1;
      int nwords = (M + 31) >> 5;
      int wpt = (nwords + 255) >> 8;
      int wlo = tid * wpt;
      int whi = min(wlo + wpt, nwords);

      int cA = 0, cB = 0;
      for (int w = wlo; w < whi; ++w) {
        unsigned int wa = 0, wb = 0;
        int rbase = w << 5;
        #pragma unroll 8
        for (int bit = 0; bit < 32; ++bit) {
          int r = rbase + bit;
          bool in = (r < M);
          float val = V(in ? (pl + r) : pl);
          if (in && r >= 1 && r <= M-2 && !(val < vp)) wa |= (1u << bit);
          if (in && r <= M-3 && !(vp < val))           wb |= (1u << bit);
        }
        abit[w] = wa; bbit[w] = wb;
        cA += __popc(wa); cB += __popc(wb);
      }
      scanA[tid] = cA; scanB[tid] = cB;
      __syncthreads();
      for (int off = 1; off < 256; off <<= 1) {
        int aa = (tid >= off) ? scanA[tid-off] : 0;
        int bb = (tid >= off) ? scanB[tid-off] : 0;
        __syncthreads();
        scanA[tid] += aa; scanB[tid] += bb;
        __syncthreads();
      }
      int offA = scanA[tid] - cA;
      int offB = scanB[tid] - cB;
      int nB = scanB[255];
      __syncthreads();

      int run = offB;
      for (int w = wlo; w < whi; ++w) {
        unsigned int wb = bbit[w];
        while (wb) {
          int bit = __ffs(wb) - 1; wb &= wb - 1;
          run++;
          Rpos[nB - run] = (unsigned short)(pl + (w << 5) + bit);
        }
      }
      __syncthreads();

      int k = offA, localK = 0;
      for (int w = wlo; w < whi; ++w) {
        unsigned int wa = abit[w];
        while (wa) {
          int bit = __ffs(wa) - 1; wa &= wa - 1;
          int pos = pl + (w << 5) + bit;
          if (k < nB && pos < (int)Rpos[k]) localK++;
          k++;
        }
      }
      if (localK) atomicAdd(&s_K, localK);
      __syncthreads();
      int K = s_K;

      k = offA;
      for (int w = wlo; w < whi; ++w) {
        unsigned int wa = abit[w];
        while (wa) {
          int bit = __ffs(wa) - 1; wa &= wa - 1;
          int pos = pl + (w << 5) + bit;
          if (k < K) {
            int pp = Rpos[k];
            unsigned short tmp = t[pos]; t[pos] = t[pp]; t[pp] = tmp;
          } else if (k == K) {
            s_LK = pos;
          }
          k++;
        }
      }
      __syncthreads();

      if (tid == 0) {
        int pi2 = s_LK;
        if (K > 0) { int rk = Rpos[K-1]; if (rk < pi2) pi2 = rk; }
        unsigned short tmp = t[pi2]; t[pi2] = t[pr-1]; t[pr-1] = tmp;
        if (pi2 - pl < pr - pi2) {
          if (pi2 + 1 <= 3) { s_slo[s_sp] = pi2 + 1; s_shi[s_sp] = pr; s_sp++; }
          s_pr = pi2 - 1;
        } else {
          s_slo[s_sp] = pl; s_shi[s_sp] = pi2 - 1; s_sp++;
          s_pl = pi2 + 1;
          if (s_pl > 3) {
            --s_sp; s_pl = s_slo[s_sp]; s_pr = s_shi[s_sp];
          }
        }
      }
    } else {
      if (pr > pl && tid <= pr - pl) vloc[tid] = V(pl + tid);
      __syncthreads();
      if (tid == 0) {
        for (int a2 = pl + 1; a2 <= pr; ++a2) {
          unsigned short vi = t[a2]; float vv = vloc[a2 - pl];
          int b2 = a2;
          while (b2 > pl && vv < vloc[b2-1-pl]) {
            t[b2] = t[b2-1]; vloc[b2-pl] = vloc[b2-1-pl]; --b2;
          }
          t[b2] = vi; vloc[b2-pl] = vv;
        }
        if (s_sp == 0) s_state = 1;
        else { --s_sp; s_pl = s_slo[s_sp]; s_pr = s_shi[s_sp]; }
      }
    }
  }

  __syncthreads();
  if (tid == 0) {
    size_t base = (size_t)row * 3;
    wd[base+0]=V(0); wd[base+1]=V(1); wd[base+2]=V(2);
    wi[base+0]=t[0]; wi[base+1]=t[1]; wi[base+2]=t[2];
  }
}

// ---------------- Kernel B2: np-f32 weights + interpolate + align + out head ----------------
__global__ void __launch_bounds__(64) interp_mlp_kernel(
    const float* __restrict__ feats,
    const float* __restrict__ wd, const int* __restrict__ wi,
    const float* __restrict__ al_w, const float* __restrict__ al_b,
    const float* __restrict__ al_g, const float* __restrict__ al_bb,
    const float* __restrict__ al_m, const float* __restrict__ al_v,
    const float* __restrict__ o_w1,
    const float* __restrict__ o_g, const float* __restrict__ o_bb,
    const float* __restrict__ o_m, const float* __restrict__ o_v,
    const float* __restrict__ o_w2, const float* __restrict__ o_b2,
    float* __restrict__ out, int NC, int NP, int B)
{
  __shared__ float s1[HID], t1[HID], s2[HID], t2[HID];
  int tx = threadIdx.x;
  if (tx < HID) {
    float sa = al_g[tx] / sqrtf(al_v[tx] + EPS_AL);
    s1[tx] = sa;
    t1[tx] = (al_b[tx] - al_m[tx]) * sa + al_bb[tx];
    float so = o_g[tx] / sqrtf(o_v[tx] + EPS_CLS);
    s2[tx] = so;
    t2[tx] = o_bb[tx] - o_m[tx] * so;
  }
  __syncthreads();
  int r = blockIdx.x * 64 + tx;
  if (r >= B * NP) return;
  int frame = r / NP;

  float bd0 = wd[(size_t)r*3+0], bd1 = wd[(size_t)r*3+1], bd2 = wd[(size_t)r*3+2];
  int   bi0 = wi[(size_t)r*3+0], bi1 = wi[(size_t)r*3+1], bi2 = wi[(size_t)r*3+2];

  float w0 = pin(__fdiv_rn(1.0f, addrn_b(fmaxf(bd0, 0.f), 1e-8f)));
  float w1 = pin(__fdiv_rn(1.0f, addrn_b(fmaxf(bd1, 0.f), 1e-8f)));
  float w2 = pin(__fdiv_rn(1.0f, addrn_b(fmaxf(bd2, 0.f), 1e-8f)));
  float wsum = addrn_b(addrn_b(w0, w1), w2);
  w0 = pin(__fdiv_rn(w0, wsum)); w1 = pin(__fdiv_rn(w1, wsum)); w2 = pin(__fdiv_rn(w2, wsum));

  const float* F = feats + (size_t)frame * NC * HID;
  const float4* F0 = (const float4*)(F + (size_t)bi0 * HID);
  const float4* F1 = (const float4*)(F + (size_t)bi1 * HID);
  const float4* F2 = (const float4*)(F + (size_t)bi2 * HID);

  float interp[HID];
  #pragma unroll
  for (int i = 0; i < 16; i++) {
    float4 a = F0[i], b = F1[i], c = F2[i];
    interp[4*i+0] = (a.x*w0 + b.x*w1) + c.x*w2;
    interp[4*i+1] = (a.y*w0 + b.y*w1) + c.y*w2;
    interp[4*i+2] = (a.z*w0 + b.z*w1) + c.z*w2;
    interp[4*i+3] = (a.w*w0 + b.w*w1) + c.w*w2;
  }

  float f[HID];
  #pragma unroll
  for (int j = 0; j < HID; j++) {
    float acc = 0.f;
    #pragma unroll
    for (int k = 0; k < HID; k++) acc = fmaf(interp[k], al_w[k*HID + j], acc);
    f[j] = relu_(acc * s1[j] + t1[j]);
  }
  float o[NCLS];
  #pragma unroll
  for (int c = 0; c < NCLS; c++) o[c] = o_b2[c];
  #pragma unroll
  for (int j = 0; j < HID; j++) {
    float acc = 0.f;
    #pragma unroll
    for (int k = 0; k < HID; k++) acc = fmaf(f[k], o_w1[k*HID + j], acc);
    float h = relu_(acc * s2[j] + t2[j]);
    #pragma unroll
    for (int c = 0; c < NCLS; c++) o[c] = fmaf(h, o_w2[j*NCLS + c], o[c]);
  }
  float4* op = (float4*)(out + (size_t)r * NCLS);
  #pragma unroll
  for (int i = 0; i < 5; i++) op[i] = make_float4(o[4*i], o[4*i+1], o[4*i+2], o[4*i+3]);
}

extern "C" void kernel_launch(void* const* d_in, const int* in_sizes, int n_in,
                              void* d_out, int out_size, void* d_ws, size_t ws_size,
                              hipStream_t stream)
{
  const float*  feats  = (const float*) d_in[0];
  const float4* coords = (const float4*)d_in[1];
  const float4* pts    = (const float4*)d_in[2];
  const float* cls_w1 = (const float*)d_in[3];
  const float* cls_g  = (const float*)d_in[4];
  const float* cls_b  = (const float*)d_in[5];
  const float* cls_m  = (const float*)d_in[6];
  const float* cls_v  = (const float*)d_in[7];
  const float* cls_w2 = (const float*)d_in[8];
  const float* cls_b2 = (const float*)d_in[9];
  const float* al_w   = (const float*)d_in[10];
  const float* al_b   = (const float*)d_in[11];
  const float* al_g   = (const float*)d_in[12];
  const float* al_bb  = (const float*)d_in[13];
  const float* al_m   = (const float*)d_in[14];
  const float* al_v   = (const float*)d_in[15];
  const float* o_w1   = (const float*)d_in[16];
  const float* o_g    = (const float*)d_in[17];
  const float* o_bb   = (const float*)d_in[18];
  const float* o_m    = (const float*)d_in[19];
  const float* o_v    = (const float*)d_in[20];
  const float* o_w2   = (const float*)d_in[21];
  const float* o_b2   = (const float*)d_in[22];

  const int B = 2;
  int RC = in_sizes[1] / 4;  int NC = RC / B;
  int RP = in_sizes[2] / 4;  int NP = RP / B;

  // ws: 1KB header | wd[RP*3] | wi[RP*3] | pd[RP*nseg] f4 | pi[RP*nseg] i4 | pmin[RP*nseg] f
  int nseg = NSEG;
  while (nseg > 1 &&
         1024 + (size_t)RP*3*8 + (size_t)RP*nseg*36 > ws_size) nseg >>= 1;

  int*   mark_cnt  = (int*)d_ws;
  int*   mark_rows = (int*)((char*)d_ws + 16);
  float* wd  = (float*)((char*)d_ws + 1024);
  int*   wi  = (int*)((char*)wd + (size_t)RP * 3 * 4);
  float4* pd = (float4*)((char*)wi + (size_t)RP * 3 * 4);
  int4*   pi = (int4*)((char*)pd + (size_t)RP * nseg * 16);
  float* pmin = (float*)((char*)pi + (size_t)RP * nseg * 16);

  hipMemsetAsync(d_ws, 0, 16, stream);

  cls_head_kernel<<<(RC + 63) / 64, 64, 0, stream>>>(
      feats, cls_w1, cls_g, cls_b, cls_m, cls_v, cls_w2, cls_b2,
      (float*)d_out, RC);

  dim3 g1((NP + 255) / 256, nseg, B);
  knn_min_kernel<<<g1, 256, 0, stream>>>(coords, pts, pmin, NC, NP, nseg);
  knn_scan_kernel<<<g1, 256, 0, stream>>>(coords, pts, pmin, pd, pi, NC, NP, nseg);

  knn_merge_kernel<<<(RP + 255) / 256, 256, 0, stream>>>(
      pd, pi, wd, wi, mark_cnt, mark_rows, RP, nseg);

  tie_resort_kernel<<<MAXMARK, 256, 0, stream>>>(coords, pts, mark_cnt, mark_rows,
                                                 wd, wi, NC, NP);

  float* out2 = (float*)d_out + (size_t)RC * NCLS;
  interp_mlp_kernel<<<(RP + 63) / 64, 64, 0, stream>>>(
      feats, wd, wi,
      al_w, al_b, al_g, al_bb, al_m, al_v,
      o_w1, o_g, o_bb, o_m, o_v, o_w2, o_b2,
      out2, NC, NP, B);
}